// Round 6
// baseline (1395.140 us; speedup 1.0000x reference)
//
#include <hip/hip_runtime.h>
#include <cstdint>
#include <cstddef>

typedef unsigned short u16;
typedef __bf16 bf16x8 __attribute__((ext_vector_type(8)));
typedef float f32x4 __attribute__((ext_vector_type(4)));

constexpr int Bz = 8, Sq = 512, Hh = 8, DKd = 64, Dm = 512, Dff = 2048, NL = 4;
constexpr int TOK = Bz * Sq;               // 4096 tokens
constexpr size_t MAT = (size_t)512 * 512;  // 262144 elems per 512x512 matrix
constexpr size_t EL  = (size_t)TOK * Dm;   // 2097152 elems per activation tensor
constexpr size_t WFT = (size_t)Dff * Dm;   // 1048576 elems per FFN matrix

__device__ __forceinline__ float bf2f(u16 u) {
  union { uint32_t i; float f; } v; v.i = (uint32_t)u << 16; return v.f;
}
__device__ __forceinline__ u16 f2bf(float f) {
  union { float f; uint32_t i; } v; v.f = f;
  uint32_t i = v.i;
  i += 0x7fffu + ((i >> 16) & 1u);   // round-to-nearest-even
  return (u16)(i >> 16);
}

// async global -> LDS, 16B per lane (global_load_lds_dwordx4)
__device__ __forceinline__ void gload16(const u16* g, u16* l) {
  __builtin_amdgcn_global_load_lds(
      (const __attribute__((address_space(1))) unsigned int*)g,
      (__attribute__((address_space(3))) unsigned int*)l, 16, 0, 0);
}

// ---------------------------------------------------------------------------
// Tiled NT GEMM: C[M,N] = A[M,K] @ Bt[N,K]^T (+bias fp32) (+relu)
// 256 threads = 4 waves (2x2); single-buffer BK=64 (proven best: dbuf and
// BK=128 both null/regress — occupancy loss eats pipeline gain).
// global_load_lds staging, XOR chunk swizzle (c ^= row&7) -> 2-way banks.
// cmode 0: plain write; 4: qkv split (Q scaled 0.125, Q->[B,H,S,DK],
//          K->+EL, V->+2EL transposed [B,H,DK,S]);
// cmode 5: embedding epilogue (+pos table).
// ---------------------------------------------------------------------------
template<int BM, int BN, int TAG>
__global__ __launch_bounds__(256)
void gemm_tile(const u16* __restrict__ A, const u16* __restrict__ Bt,
               const float* __restrict__ bias, u16* __restrict__ C,
               int K, int lda, long long sA, int ldb, long long sB,
               int ldc, long long sC, int cmode, int relu, int colofs,
               const u16* A2, int xsplit, const float* __restrict__ posp)
{
  constexpr int HM = BM / 2, HN = BN / 2, MI = HM / 16, NI = HN / 16;
  __shared__ __align__(16) u16 As[BM * 64];
  __shared__ __align__(16) u16 Bs[BN * 64];
  const int bz = blockIdx.z;
  const u16* Abase = A;
  int colbase;
  if (A2 && (int)blockIdx.x >= xsplit) {
    Abase = A2;
    colbase = 512 + ((int)blockIdx.x - xsplit) * BN;
  } else {
    colbase = colofs + (int)blockIdx.x * BN;
  }
  const u16* Ab = Abase + (size_t)bz * (size_t)sA + (size_t)(blockIdx.y * BM) * lda;
  const u16* Bb = Bt + (size_t)bz * (size_t)sB + (size_t)colbase * ldb;
  const int tid  = threadIdx.x;
  const int lane = tid & 63;
  const int wid  = tid >> 6;
  const int l15  = lane & 15;
  const int quad = lane >> 4;
  const int wm   = wid >> 1, wn = wid & 1;

  f32x4 acc[MI][NI] = {};

  for (int k0 = 0; k0 < K; k0 += 64) {
#pragma unroll
    for (int i = 0; i < BM / 32; ++i) {          // A: BM rows x 64, 8 chunks/row
      const int s = tid + i * 256;
      const int row = s >> 3, c = (s & 7) ^ (row & 7);
      gload16(Ab + (size_t)row * lda + k0 + c * 8, As + s * 8);
    }
#pragma unroll
    for (int i = 0; i < BN / 32; ++i) {
      const int s = tid + i * 256;
      const int row = s >> 3, c = (s & 7) ^ (row & 7);
      gload16(Bb + (size_t)row * ldb + k0 + c * 8, Bs + s * 8);
    }
    __syncthreads();
#pragma unroll
    for (int kk = 0; kk < 2; ++kk) {
      bf16x8 af[MI], bfr[NI];
#pragma unroll
      for (int mi = 0; mi < MI; ++mi) {
        const int ra = wm * HM + mi * 16 + l15;
        af[mi] = *(const bf16x8*)(As + ra * 64 + (((kk * 4 + quad) ^ (ra & 7))) * 8);
      }
#pragma unroll
      for (int ni = 0; ni < NI; ++ni) {
        const int rb = wn * HN + ni * 16 + l15;
        bfr[ni] = *(const bf16x8*)(Bs + rb * 64 + (((kk * 4 + quad) ^ (rb & 7))) * 8);
      }
#pragma unroll
      for (int mi = 0; mi < MI; ++mi)
#pragma unroll
        for (int ni = 0; ni < NI; ++ni)
          acc[mi][ni] = __builtin_amdgcn_mfma_f32_16x16x32_bf16(af[mi], bfr[ni], acc[mi][ni], 0, 0, 0);
    }
    __syncthreads();
  }

  const int rblk = blockIdx.y * BM + wm * HM + quad * 4;
#pragma unroll
  for (int ni = 0; ni < NI; ++ni) {
    const int colx = colbase + wn * HN + ni * 16 + l15;
    const float bv = bias ? bias[colx] : 0.f;
#pragma unroll
    for (int mi = 0; mi < MI; ++mi) {
#pragma unroll
      for (int r = 0; r < 4; ++r) {
        float v = acc[mi][ni][r] + bv;
        if (relu) v = fmaxf(v, 0.f);
        const int grow = rblk + mi * 16 + r;
        size_t off;
        if (cmode == 0) {
          off = (size_t)bz * (size_t)sC + (size_t)grow * ldc + colx;
        } else if (cmode == 5) {  // embedding: + pos table, contiguous enc|dec rows
          const int s = grow & 511;
          v += posp[(size_t)(s + 1) * 512 + colx];
          off = (size_t)grow * 512 + colx;
        } else {  // 4: qkv scatter; fold 1/sqrt(DK)=0.125 into Q
          const int sec = colx >> 9, n = colx & 511, h = n >> 6, d = n & 63;
          const int b = grow >> 9, s = grow & 511;
          if (sec == 0) v *= 0.125f;
          if (sec < 2) off = (size_t)sec * EL + (size_t)b * 262144 + (size_t)h * 32768 + (size_t)s * 64 + d;
          else         off = 2 * EL + (size_t)b * 262144 + (size_t)h * 32768 + (size_t)d * 512 + s;
        }
        C[off] = f2bf(v);
      }
    }
  }
}

// ---------------------------------------------------------------------------
// Fused row-GEMM + residual + LayerNorm:
//   out[r,:] = LN( resid[r,:] + A[r,:]@Bt^T + bias )   (torch ddof=1 LN)
// Block = 16 full rows x 512 cols (grid 256, 1 block/CU); 4 waves split N
// (128 cols each). B slice [512 x 64] staged per K-step (64 KB LDS);
// A slice [16 x 64] (2 KB). Epilogue: per-row stats via 16-lane shfl +
// cross-wave LDS reduction; normalized tile repacked in LDS (reusing Bs)
// for coalesced uint4 stores. out32: final fp32 output instead of bf16.
// ---------------------------------------------------------------------------
template<int K, int TAG>
__global__ __launch_bounds__(256)
void gemm_row_ln(const u16* __restrict__ A, const u16* __restrict__ Bt,
                 const float* __restrict__ bias, const u16* __restrict__ resid,
                 const float* __restrict__ g, const float* __restrict__ bb,
                 u16* __restrict__ out, float* __restrict__ out32)
{
  __shared__ __align__(16) u16 Bs[512 * 64];   // 64 KB: B K-slice
  __shared__ __align__(16) u16 As[16 * 64];    // 2 KB: A K-slice
  __shared__ float redS[4][16], redQ[4][16];
  const int tid = threadIdx.x, lane = tid & 63, wid = tid >> 6;
  const int l15 = lane & 15, quad = lane >> 4;
  const int r0 = blockIdx.x * 16;
  const u16* Ab = A + (size_t)r0 * K;

  f32x4 acc[8] = {};
  for (int k0 = 0; k0 < K; k0 += 64) {
    if (tid < 128) {                            // A: 16 rows x 64
      const int row = tid >> 3, c = (tid & 7) ^ (row & 7);
      gload16(Ab + (size_t)row * K + k0 + c * 8, As + tid * 8);
    }
#pragma unroll
    for (int i = 0; i < 16; ++i) {              // B: 512 rows x 64
      const int s = tid + i * 256;
      const int row = s >> 3, c = (s & 7) ^ (row & 7);
      gload16(Bt + (size_t)row * K + k0 + c * 8, Bs + s * 8);
    }
    __syncthreads();
#pragma unroll
    for (int kk = 0; kk < 2; ++kk) {
      bf16x8 af = *(const bf16x8*)(As + l15 * 64 + (((kk * 4 + quad) ^ (l15 & 7))) * 8);
#pragma unroll
      for (int ni = 0; ni < 8; ++ni) {
        const int rb = wid * 128 + ni * 16 + l15;
        bf16x8 bf = *(const bf16x8*)(Bs + rb * 64 + (((kk * 4 + quad) ^ (rb & 7))) * 8);
        acc[ni] = __builtin_amdgcn_mfma_f32_16x16x32_bf16(af, bf, acc[ni], 0, 0, 0);
      }
    }
    __syncthreads();
  }

  // z = acc + bias + resid; accumulate row stats
  float z[8][4];
  float s[4] = {0.f, 0.f, 0.f, 0.f}, q[4] = {0.f, 0.f, 0.f, 0.f};
#pragma unroll
  for (int ni = 0; ni < 8; ++ni) {
    const int colx = wid * 128 + ni * 16 + l15;
    const float bv = bias[colx];
#pragma unroll
    for (int r = 0; r < 4; ++r) {
      const int row = quad * 4 + r;
      const float zz = acc[ni][r] + bv + bf2f(resid[(size_t)(r0 + row) * 512 + colx]);
      z[ni][r] = zz; s[r] += zz; q[r] += zz * zz;
    }
  }
#pragma unroll
  for (int r = 0; r < 4; ++r) {
#pragma unroll
    for (int m = 8; m > 0; m >>= 1) {
      s[r] += __shfl_xor(s[r], m);
      q[r] += __shfl_xor(q[r], m);
    }
  }
  if (l15 == 0) {
#pragma unroll
    for (int r = 0; r < 4; ++r) {
      redS[wid][quad * 4 + r] = s[r];
      redQ[wid][quad * 4 + r] = q[r];
    }
  }
  __syncthreads();
  float mean[4], inv[4];
#pragma unroll
  for (int r = 0; r < 4; ++r) {
    const int row = quad * 4 + r;
    const float sT = redS[0][row] + redS[1][row] + redS[2][row] + redS[3][row];
    const float qT = redQ[0][row] + redQ[1][row] + redQ[2][row] + redQ[3][row];
    mean[r] = sT * (1.f / 512.f);
    const float ssc = fmaxf(qT - 512.f * mean[r] * mean[r], 0.f);
    const float stdv = sqrtf(ssc * (1.f / 511.f));
    inv[r] = 1.f / (stdv + 1e-6f);
  }
  __syncthreads();                 // all waves done with redS/redQ + Bs reads
  u16* Ls = Bs;                    // repack normalized tile for coalesced store
#pragma unroll
  for (int ni = 0; ni < 8; ++ni) {
    const int colx = wid * 128 + ni * 16 + l15;
    const float gv = g[colx], bvv = bb[colx];
#pragma unroll
    for (int r = 0; r < 4; ++r) {
      const int row = quad * 4 + r;
      Ls[row * 512 + colx] = f2bf(gv * (z[ni][r] - mean[r]) * inv[r] + bvv);
    }
  }
  __syncthreads();
  if (out32) {
#pragma unroll
    for (int i = 0; i < 4; ++i) {
      const int idx = tid + i * 256;           // uint4 index over 16 KB tile
      const int row = idx >> 6, c8 = idx & 63;
      uint4 raw = *(const uint4*)(Ls + (size_t)row * 512 + c8 * 8);
      const u16* h = (const u16*)&raw;
      float4 o0 = { bf2f(h[0]), bf2f(h[1]), bf2f(h[2]), bf2f(h[3]) };
      float4 o1 = { bf2f(h[4]), bf2f(h[5]), bf2f(h[6]), bf2f(h[7]) };
      float* dst = out32 + (size_t)(r0 + row) * 512 + c8 * 8;
      *(float4*)dst = o0;
      *(float4*)(dst + 4) = o1;
    }
  } else {
#pragma unroll
    for (int i = 0; i < 4; ++i) {
      const int idx = tid + i * 256;
      const int row = idx >> 6, c8 = idx & 63;
      *(uint4*)(out + (size_t)(r0 + row) * 512 + c8 * 8) =
          *(const uint4*)(Ls + (size_t)row * 512 + c8 * 8);
    }
  }
}

// ---------------------------------------------------------------------------
// Fused attention: per block = (q-tile of 64 rows, one (b,h)).
// ctx[b,s,h*64+d] = softmax(mask(Q K^T)) V.  Q pre-scaled by 0.125.
// ---------------------------------------------------------------------------
__global__ __launch_bounds__(256)
void flash_attn(const u16* __restrict__ q, const u16* __restrict__ k,
                const u16* __restrict__ v, const unsigned char* __restrict__ pad,
                u16* __restrict__ ctx, int mtype)
{
  __shared__ __align__(16) u16 KVs[8192];      // 16 KB: K or V chunk (swizzled)
  __shared__ __align__(16) u16 Pw[4][2048];    // 4 KB per wave: P tile 16x128
  const int bh = blockIdx.y, b = bh >> 3, h = bh & 7;
  const int qt = blockIdx.x;
  const int tid = threadIdx.x, lane = tid & 63, wid = tid >> 6;
  const int l15 = lane & 15, quad = lane >> 4;
  const size_t bho = (size_t)bh * 32768;
  const int qrow = qt * 64 + wid * 16 + l15;       // A-operand row (this lane)
  const int qcd  = qt * 64 + wid * 16 + quad * 4;  // C-layout row base

  unsigned char* Ps = (unsigned char*)&Pw[0][0];
  if (tid < 128) ((uchar4*)Ps)[tid] = ((const uchar4*)(pad + b * 512))[tid];

  bf16x8 aq0 = *(const bf16x8*)(q + bho + (size_t)qrow * 64 + quad * 8);
  bf16x8 aq1 = *(const bf16x8*)(q + bho + (size_t)qrow * 64 + 32 + quad * 8);

  f32x4 S[32];
#pragma unroll
  for (int kc = 0; kc < 4; ++kc) {
    __syncthreads();
#pragma unroll
    for (int i = 0; i < 4; ++i) {             // stage K chunk [128 keys][64]
      const int s = tid + i * 256;
      const int row = s >> 3, c = (s & 7) ^ (row & 7);
      gload16(k + bho + (size_t)(kc * 128 + row) * 64 + c * 8, KVs + s * 8);
    }
    __syncthreads();
#pragma unroll
    for (int t = 0; t < 8; ++t) {
      const int sw = l15 & 7;
      bf16x8 b0 = *(const bf16x8*)(KVs + (t * 16 + l15) * 64 + (quad ^ sw) * 8);
      bf16x8 b1 = *(const bf16x8*)(KVs + (t * 16 + l15) * 64 + ((4 + quad) ^ sw) * 8);
      f32x4 z = {0.f, 0.f, 0.f, 0.f};
      z = __builtin_amdgcn_mfma_f32_16x16x32_bf16(aq0, b0, z, 0, 0, 0);
      S[kc * 8 + t] = __builtin_amdgcn_mfma_f32_16x16x32_bf16(aq1, b1, z, 0, 0, 0);
    }
  }

  unsigned pm = 0u;
#pragma unroll
  for (int t = 0; t < 32; ++t) pm |= (unsigned)(Ps[t * 16 + l15] != 0) << t;

  float inv[4];
#pragma unroll
  for (int r = 0; r < 4; ++r) {
    const int qg = qcd + r;
    float mx = -3.0e38f;
#pragma unroll
    for (int t = 0; t < 32; ++t) {
      const int col = t * 16 + l15;
      const bool m = ((pm >> t) & 1u) || (mtype == 1 && col > qg);
      const float val = m ? -1e9f : S[t][r];
      S[t][r] = val;
      mx = fmaxf(mx, val);
    }
#pragma unroll
    for (int o = 8; o > 0; o >>= 1) mx = fmaxf(mx, __shfl_xor(mx, o));
    float sm = 0.f;
#pragma unroll
    for (int t = 0; t < 32; ++t) { const float e = __expf(S[t][r] - mx); S[t][r] = e; sm += e; }
#pragma unroll
    for (int o = 8; o > 0; o >>= 1) sm += __shfl_xor(sm, o);
    inv[r] = 1.f / sm;
  }

  f32x4 O[4] = {};
  u16* myP = &Pw[wid][0];
#pragma unroll
  for (int kc = 0; kc < 4; ++kc) {
    __syncthreads();
#pragma unroll
    for (int i = 0; i < 4; ++i) {             // stage V chunk [64 dk][128 keys]
      const int s = tid + i * 256;
      const int row = s >> 4, c = (s & 15) ^ (row & 15);
      gload16(v + bho + (size_t)row * 512 + kc * 128 + c * 8, KVs + s * 8);
    }
#pragma unroll
    for (int t = 0; t < 8; ++t)
#pragma unroll
      for (int r = 0; r < 4; ++r) {
        const int rowq = quad * 4 + r;
        const int c = 2 * t + (l15 >> 3);
        myP[rowq * 128 + (c ^ rowq) * 8 + (l15 & 7)] = f2bf(S[kc * 8 + t][r] * inv[r]);
      }
    __syncthreads();
#pragma unroll
    for (int kk = 0; kk < 4; ++kk) {
      bf16x8 ap = *(const bf16x8*)(myP + l15 * 128 + ((kk * 4 + quad) ^ l15) * 8);
#pragma unroll
      for (int ni = 0; ni < 4; ++ni) {
        bf16x8 bv = *(const bf16x8*)(KVs + (ni * 16 + l15) * 128 + ((kk * 4 + quad) ^ l15) * 8);
        O[ni] = __builtin_amdgcn_mfma_f32_16x16x32_bf16(ap, bv, O[ni], 0, 0, 0);
      }
    }
  }

  const int token = b * 512 + qcd;
#pragma unroll
  for (int ni = 0; ni < 4; ++ni)
#pragma unroll
    for (int r = 0; r < 4; ++r)
      ctx[(size_t)(token + r) * 512 + h * 64 + ni * 16 + l15] = f2bf(O[ni][r]);
}

// ---------------------------------------------------------------------------
// Merged setup, flat 1-D grid of 7440 fat blocks:
// b<3072   -> weight transposes, 64x64 tile/block (16 floats/thread).
// b<7168   -> fp32->bf16 convert of 4 FFN groups, 16 elems/thread.
// b<7184   -> ewb (identity-augmented embed weight [512,64]) + biasE.
// b<7440   -> embed-pre: x fp32 [8192,32] -> xbf bf16 [8192,64] + pad flags.
// ---------------------------------------------------------------------------
__global__ __launch_bounds__(256)
void prep_weights(const float* __restrict__ s0, const float* __restrict__ s1,
                  const float* __restrict__ s2, const float* __restrict__ s3,
                  const float* __restrict__ s4, const float* __restrict__ s5,
                  u16* __restrict__ outT,
                  const float* __restrict__ c0, const float* __restrict__ c1,
                  const float* __restrict__ c2, const float* __restrict__ c3,
                  u16* __restrict__ outC,
                  const float* __restrict__ ew, const float* __restrict__ eb,
                  u16* __restrict__ ewb, float* __restrict__ biasE,
                  const float* __restrict__ xe, const float* __restrict__ xd,
                  u16* __restrict__ xbf,
                  unsigned char* __restrict__ pe, unsigned char* __restrict__ pd)
{
  __shared__ float tile[64][65];
  const int blk = blockIdx.x;
  const int tid = threadIdx.x;
  if (blk < 3072) {                       // transpose: mat z, 64x64 tile
    const int z = blk >> 6, t = blk & 63;
    const int tx = t & 7, ty = t >> 3;
    const float* src; int zi;
    if      (z < 12) { src = s0; zi = z; }
    else if (z < 24) { src = s1; zi = z - 12; }
    else if (z < 36) { src = s2; zi = z - 24; }
    else if (z < 40) { src = s3; zi = z - 36; }
    else if (z < 44) { src = s4; zi = z - 40; }
    else             { src = s5; zi = z - 44; }
    const float* in = src + (size_t)zi * MAT;
    u16* o = outT + (size_t)z * MAT;
    const int rr = tid >> 4, slot = tid & 15;
#pragma unroll
    for (int j = 0; j < 4; ++j) {
      const int row = j * 16 + rr;
      float4 v = *(const float4*)(in + (size_t)(ty * 64 + row) * 512 + tx * 64 + slot * 4);
      tile[row][slot * 4 + 0] = v.x; tile[row][slot * 4 + 1] = v.y;
      tile[row][slot * 4 + 2] = v.z; tile[row][slot * 4 + 3] = v.w;
    }
    __syncthreads();
#pragma unroll
    for (int j = 0; j < 4; ++j) {
      const int row = j * 16 + rr;
      ushort4 w;
      w.x = f2bf(tile[slot * 4 + 0][row]);
      w.y = f2bf(tile[slot * 4 + 1][row]);
      w.z = f2bf(tile[slot * 4 + 2][row]);
      w.w = f2bf(tile[slot * 4 + 3][row]);
      *(ushort4*)(o + (size_t)(tx * 64 + row) * 512 + ty * 64 + slot * 4) = w;
    }
  } else if (blk < 7168) {                // convert: 16 elems/thread
    const int L = blk - 3072;             // 0..4095
    const size_t e0 = (size_t)L * 4096 + (size_t)tid * 16;
    const int tens = (int)(e0 >> 22);     // 4*WFT = 2^22
    const size_t local = e0 & (4 * WFT - 1);
    const float* srcs[4] = { c0, c1, c2, c3 };
    const float* src = srcs[tens];
    u16* dst = outC + (size_t)tens * (4 * WFT) + local;
#pragma unroll
    for (int j = 0; j < 4; ++j) {
      float4 v = *(const float4*)(src + local + j * 4);
      ushort4 u = { f2bf(v.x), f2bf(v.y), f2bf(v.z), f2bf(v.w) };
      *(ushort4*)(dst + j * 4) = u;
    }
  } else if (blk < 7184) {                // ewb + biasE
    const int j = blk - 7168;             // 0..15
    const int row = j * 32 + (tid >> 3);  // 0..511
    const int c0i = (tid & 7) * 8;
#pragma unroll
    for (int k = 0; k < 8; ++k) {
      const int c = c0i + k;
      float v;
      if (row < 32) v = (c == row) ? 1.f : 0.f;
      else          v = (c < 32) ? ew[(size_t)(row - 32) * 32 + c] : 0.f;
      ewb[(size_t)row * 64 + c] = f2bf(v);
    }
    if (j == 0) {
      biasE[tid]       = (tid < 32) ? 0.f : eb[tid - 32];
      biasE[tid + 256] = eb[tid + 256 - 32];
    }
  } else {                                // embed-pre
    const int bxy = blk - 7184;           // 0..255
    const int lw = tid & 31;
#pragma unroll
    for (int rep = 0; rep < 4; ++rep) {
      const int rr0 = bxy * 32 + rep * 8 + (tid >> 5);  // 0..8191
      const float* xsrc = (rr0 < 4096) ? xe : xd;
      const int rr = rr0 & 4095;
      const float v = xsrc[(size_t)rr * 32 + lw];
      float sm = v;
#pragma unroll
      for (int o = 16; o > 0; o >>= 1) sm += __shfl_xor(sm, o);
      if (lw == 0) {
        unsigned char* pv = (rr0 < 4096) ? pe : pd;
        pv[rr] = (sm <= -9999.f) ? 1 : 0;
      }
      u16* orow = xbf + (size_t)rr0 * 64;
      orow[lw] = f2bf(v);
      orow[32 + lw] = 0;
    }
  }
}

extern "C" void kernel_launch(void* const* d_in, const int* in_sizes, int n_in,
                              void* d_out, int out_size, void* d_ws, size_t ws_size,
                              hipStream_t stream)
{
  (void)in_sizes; (void)n_in; (void)out_size;
  const float* enc_in   = (const float*)d_in[0];
  const float* dec_in   = (const float*)d_in[1];
  const float* emb_w    = (const float*)d_in[2];
  const float* emb_b    = (const float*)d_in[3];
  const float* pos      = (const float*)d_in[4];
  const float* e_qkv_w  = (const float*)d_in[5];
  const float* e_qkv_b  = (const float*)d_in[6];
  const float* e_pw     = (const float*)d_in[7];
  const float* e_pb     = (const float*)d_in[8];
  const float* e_ln1    = (const float*)d_in[9];
  const float* e_w1     = (const float*)d_in[10];
  const float* e_b1     = (const float*)d_in[11];
  const float* e_w2     = (const float*)d_in[12];
  const float* e_b2     = (const float*)d_in[13];
  const float* e_ln2    = (const float*)d_in[14];
  const float* ds_qkv_w = (const float*)d_in[15];
  const float* ds_qkv_b = (const float*)d_in[16];
  const float* ds_pw    = (const float*)d_in[17];
  const float* ds_pb    = (const float*)d_in[18];
  const float* d_ln1    = (const float*)d_in[19];
  const float* dc_qkv_w = (const float*)d_in[20];
  const float* dc_qkv_b = (const float*)d_in[21];
  const float* dc_pw    = (const float*)d_in[22];
  const float* dc_pb    = (const float*)d_in[23];
  const float* d_ln2    = (const float*)d_in[24];
  const float* d_w1     = (const float*)d_in[25];
  const float* d_b1     = (const float*)d_in[26];
  const float* d_w2     = (const float*)d_in[27];
  const float* d_b2     = (const float*)d_in[28];
  const float* d_ln3    = (const float*)d_in[29];

  u16* ws  = (u16*)d_ws;
  u16* enc = ws;             // EL   (enc|dec contiguous -> one embed GEMM)
  u16* dec = ws + EL;        // EL
  u16* qb  = ws + 2 * EL;    // EL [B,H,S,DK]  (K at +EL, V^T at +2EL)
  u16* kb  = ws + 3 * EL;    // EL [B,H,S,DK]
  u16* vT  = ws + 4 * EL;    // EL [B,H,DK,S]
  u16* ctx = ws + 5 * EL;    // EL [B,S,H*DK]
  u16* hff = ws + 7 * EL;    // 4*EL [B,S,Dff]
  u16* wT  = ws + 15 * EL;   // 6*EL: 48 transposed bf16 512x512 matrices
  unsigned char* padE = (unsigned char*)(ws + 21 * EL);   // TOK bytes
  unsigned char* padD = padE + TOK;                       // TOK bytes
  u16* xbf   = ws + 21 * EL + 8192;        // 8192x64 bf16 (512K elems)
  u16* ewb   = xbf + (size_t)8192 * 64;    // 512x64 bf16 (32K elems)
  float* biasE = (float*)(ewb + 32768);    // 512 fp32
  u16* wfAll = ws + 22 * EL; // 8*EL: [e_w1(4L), e_w2(4L), d_w1(4L), d_w2(4L)] bf16
  if (ws_size < 30 * EL * 2 + 2 * TOK) return;

  prep_weights<<<7440, 256, 0, stream>>>(
      e_qkv_w, ds_qkv_w, dc_qkv_w, e_pw, ds_pw, dc_pw, wT,
      e_w1, e_w2, d_w1, d_w2, wfAll,
      emb_w, emb_b, ewb, biasE,
      enc_in, dec_in, xbf, padE, padD);
  // embedding as identity-augmented GEMM: [8192,64] @ ewb[512,64]^T + biasE + pos
  gemm_tile<64, 128, 4><<<dim3(4, 128, 1), 256, 0, stream>>>(
      xbf, ewb, biasE, enc, 64, 64, 0, 64, 0, 512, 0, 5, 0, 0, nullptr, 0, pos);

  // full MHA sublayer: x = LN(x + proj(flash_attn(q(qsrc), k(kvsrc), v(kvsrc))))
  auto attention = [&](const u16* qsrc, const u16* kvsrc, const u16* wq3, const float* b3,
                       const u16* pwT, const float* pb, const float* ln,
                       const unsigned char* pad, int mtype, u16* x) {
    if (qsrc == kvsrc) {
      // fused QKV: [4096,512] x [1536,512]^T -> qb/kb/vT
      gemm_tile<64, 128, 0><<<dim3(12, 64, 1), 256, 0, stream>>>(
          qsrc, wq3, b3, qb, 512, 512, 0, 512, 0, 0, 0, 4, 0, 0, nullptr, 0, nullptr);
    } else {
      // merged cross Q (x<4: A=qsrc, cols 0..511) + KV (x>=4: A=kvsrc, cols 512..1535)
      gemm_tile<64, 128, 0><<<dim3(12, 64, 1), 256, 0, stream>>>(
          qsrc, wq3, b3, qb, 512, 512, 0, 512, 0, 0, 0, 4, 0, 0, kvsrc, 4, nullptr);
    }
    flash_attn<<<dim3(8, 64), 256, 0, stream>>>(qb, kb, vT, pad, ctx, mtype);
    // fused proj + residual + LN (writes x in place)
    gemm_row_ln<512, 0><<<256, 256, 0, stream>>>(
        ctx, pwT, pb, x, ln, ln + 512, x, nullptr);
  };

  auto ffn = [&](u16* x, const u16* w1b, const float* b1, const u16* w2b,
                 const float* b2, const float* ln, float* o32) {
    gemm_tile<64, 128, 2><<<dim3(16, 64, 1), 256, 0, stream>>>(
        x, w1b, b1, hff, 512, 512, 0, 512, 0, 2048, 0, 0, 1, 0, nullptr, 0, nullptr);
    // fused FFN2 + residual + LN
    gemm_row_ln<2048, 1><<<256, 256, 0, stream>>>(
        hff, w2b, b2, x, ln, ln + 512, x, o32);
  };

  for (int i = 0; i < NL; ++i) {
    attention(enc, enc, wT + (size_t)(i * 3) * MAT, e_qkv_b + i * 3 * 512,
              wT + (size_t)(36 + i) * MAT, e_pb + i * 512, e_ln1 + i * 1024, padE, 0, enc);
    ffn(enc, wfAll + (size_t)i * WFT, e_b1 + i * Dff,
        wfAll + 4 * WFT + (size_t)i * WFT, e_b2 + i * Dm, e_ln2 + i * 1024, nullptr);
  }

  for (int i = 0; i < NL; ++i) {
    attention(dec, dec, wT + (size_t)(12 + i * 3) * MAT, ds_qkv_b + i * 3 * 512,
              wT + (size_t)(40 + i) * MAT, ds_pb + i * 512, d_ln1 + i * 1024, padD, 1, dec);
    attention(dec, enc, wT + (size_t)(24 + i * 3) * MAT, dc_qkv_b + i * 3 * 512,
              wT + (size_t)(44 + i) * MAT, dc_pb + i * 512, d_ln2 + i * 1024, padE, 2, dec);
    ffn(dec, wfAll + 8 * WFT + (size_t)i * WFT, d_b1 + i * Dff,
        wfAll + 12 * WFT + (size_t)i * WFT, d_b2 + i * Dm, d_ln3 + i * 1024,
        (i == NL - 1) ? (float*)d_out : nullptr);
  }
}

// Round 7
// 1255.226 us; speedup vs baseline: 1.1115x; 1.1115x over previous
//
#include <hip/hip_runtime.h>
#include <cstdint>
#include <cstddef>

typedef unsigned short u16;
typedef __bf16 bf16x8 __attribute__((ext_vector_type(8)));
typedef float f32x4 __attribute__((ext_vector_type(4)));

constexpr int Bz = 8, Sq = 512, Hh = 8, DKd = 64, Dm = 512, Dff = 2048, NL = 4;
constexpr int TOK = Bz * Sq;               // 4096 tokens
constexpr size_t MAT = (size_t)512 * 512;  // 262144 elems per 512x512 matrix
constexpr size_t EL  = (size_t)TOK * Dm;   // 2097152 elems per activation tensor
constexpr size_t WFT = (size_t)Dff * Dm;   // 1048576 elems per FFN matrix

__device__ __forceinline__ float bf2f(u16 u) {
  union { uint32_t i; float f; } v; v.i = (uint32_t)u << 16; return v.f;
}
__device__ __forceinline__ u16 f2bf(float f) {
  union { float f; uint32_t i; } v; v.f = f;
  uint32_t i = v.i;
  i += 0x7fffu + ((i >> 16) & 1u);   // round-to-nearest-even
  return (u16)(i >> 16);
}

// async global -> LDS, 16B per lane (global_load_lds_dwordx4)
__device__ __forceinline__ void gload16(const u16* g, u16* l) {
  __builtin_amdgcn_global_load_lds(
      (const __attribute__((address_space(1))) unsigned int*)g,
      (__attribute__((address_space(3))) unsigned int*)l, 16, 0, 0);
}

// ---------------------------------------------------------------------------
// Tiled NT GEMM: C[M,N] = A[M,K] @ Bt[N,K]^T (+bias fp32) (+relu)
// 256 threads = 4 waves (2x2); single-buffer BK=64 (proven best: dbuf and
// BK=128 both null/regress — occupancy loss eats pipeline gain; LN-fused
// full-row tiles regress 113us — B-reuse collapses).
// global_load_lds staging, XOR chunk swizzle (c ^= row&7) -> 2-way banks.
// cmode 0: plain write; 4: qkv split (Q scaled 0.125, Q->[B,H,S,DK],
//          K->+EL, V->+2EL transposed [B,H,DK,S]; V-section blocks
//          (colbase>=1024) repack the tile in LDS and store V^T as
//          128B-contiguous runs instead of 2B scatter);
// cmode 5: embedding epilogue (+pos table).
// TAG only differentiates kernel names for per-role rocprof attribution.
// ---------------------------------------------------------------------------
template<int BM, int BN, int TAG>
__global__ __launch_bounds__(256)
void gemm_tile(const u16* __restrict__ A, const u16* __restrict__ Bt,
               const float* __restrict__ bias, u16* __restrict__ C,
               int K, int lda, long long sA, int ldb, long long sB,
               int ldc, long long sC, int cmode, int relu, int colofs,
               const u16* A2, int xsplit, const float* __restrict__ posp)
{
  constexpr int HM = BM / 2, HN = BN / 2, MI = HM / 16, NI = HN / 16;
  __shared__ __align__(16) u16 As[BM * 64];
  __shared__ __align__(16) u16 Bs[BN * 64];
  const int bz = blockIdx.z;
  const u16* Abase = A;
  int colbase;
  if (A2 && (int)blockIdx.x >= xsplit) {
    Abase = A2;
    colbase = 512 + ((int)blockIdx.x - xsplit) * BN;
  } else {
    colbase = colofs + (int)blockIdx.x * BN;
  }
  const u16* Ab = Abase + (size_t)bz * (size_t)sA + (size_t)(blockIdx.y * BM) * lda;
  const u16* Bb = Bt + (size_t)bz * (size_t)sB + (size_t)colbase * ldb;
  const int tid  = threadIdx.x;
  const int lane = tid & 63;
  const int wid  = tid >> 6;
  const int l15  = lane & 15;
  const int quad = lane >> 4;
  const int wm   = wid >> 1, wn = wid & 1;

  f32x4 acc[MI][NI] = {};

  for (int k0 = 0; k0 < K; k0 += 64) {
#pragma unroll
    for (int i = 0; i < BM / 32; ++i) {          // A: BM rows x 64, 8 chunks/row
      const int s = tid + i * 256;
      const int row = s >> 3, c = (s & 7) ^ (row & 7);
      gload16(Ab + (size_t)row * lda + k0 + c * 8, As + s * 8);
    }
#pragma unroll
    for (int i = 0; i < BN / 32; ++i) {
      const int s = tid + i * 256;
      const int row = s >> 3, c = (s & 7) ^ (row & 7);
      gload16(Bb + (size_t)row * ldb + k0 + c * 8, Bs + s * 8);
    }
    __syncthreads();
#pragma unroll
    for (int kk = 0; kk < 2; ++kk) {
      bf16x8 af[MI], bfr[NI];
#pragma unroll
      for (int mi = 0; mi < MI; ++mi) {
        const int ra = wm * HM + mi * 16 + l15;
        af[mi] = *(const bf16x8*)(As + ra * 64 + (((kk * 4 + quad) ^ (ra & 7))) * 8);
      }
#pragma unroll
      for (int ni = 0; ni < NI; ++ni) {
        const int rb = wn * HN + ni * 16 + l15;
        bfr[ni] = *(const bf16x8*)(Bs + rb * 64 + (((kk * 4 + quad) ^ (rb & 7))) * 8);
      }
#pragma unroll
      for (int mi = 0; mi < MI; ++mi)
#pragma unroll
        for (int ni = 0; ni < NI; ++ni)
          acc[mi][ni] = __builtin_amdgcn_mfma_f32_16x16x32_bf16(af[mi], bfr[ni], acc[mi][ni], 0, 0, 0);
    }
    __syncthreads();
  }

  const int rblk = blockIdx.y * BM + wm * HM + quad * 4;
  if (cmode != 4 || colbase < 1024) {
#pragma unroll
    for (int ni = 0; ni < NI; ++ni) {
      const int colx = colbase + wn * HN + ni * 16 + l15;
      const float bv = bias ? bias[colx] : 0.f;
#pragma unroll
      for (int mi = 0; mi < MI; ++mi) {
#pragma unroll
        for (int r = 0; r < 4; ++r) {
          float v = acc[mi][ni][r] + bv;
          if (relu) v = fmaxf(v, 0.f);
          const int grow = rblk + mi * 16 + r;
          size_t off;
          if (cmode == 0) {
            off = (size_t)bz * (size_t)sC + (size_t)grow * ldc + colx;
          } else if (cmode == 5) {  // embedding: + pos table, contiguous enc|dec
            const int s = grow & 511;
            v += posp[(size_t)(s + 1) * 512 + colx];
            off = (size_t)grow * 512 + colx;
          } else {  // 4: Q/K sections; fold 1/sqrt(DK)=0.125 into Q
            const int sec = colx >> 9, n = colx & 511, h = n >> 6, d = n & 63;
            const int b = grow >> 9, s = grow & 511;
            if (sec == 0) v *= 0.125f;
            off = (size_t)sec * EL + (size_t)b * 262144 + (size_t)h * 32768 + (size_t)s * 64 + d;
          }
          C[off] = f2bf(v);
        }
      }
    }
  } else {
    // cmode 4, V section (colbase>=1024): repack 64x128 tile in LDS
    // (swizzled: elem(col,srow) at col*64 + (srow ^ ((col&7)<<3))),
    // then store V^T[b,h,d,s] as 8-lane x 16B = 128B contiguous runs.
    u16* Ls = Bs;   // 16 KB free after K-loop's trailing barrier
#pragma unroll
    for (int ni = 0; ni < NI; ++ni) {
      const int col = wn * HN + ni * 16 + l15;
      const float bv = bias ? bias[colbase + col] : 0.f;
#pragma unroll
      for (int mi = 0; mi < MI; ++mi) {
#pragma unroll
        for (int r = 0; r < 4; ++r) {
          const int srow = wm * HM + mi * 16 + quad * 4 + r;
          Ls[col * 64 + (srow ^ ((col & 7) << 3))] = f2bf(acc[mi][ni][r] + bv);
        }
      }
    }
    __syncthreads();
    const int gb = (blockIdx.y * BM) >> 9, s0 = (blockIdx.y * BM) & 511;
    const int grp = tid >> 3, sl = tid & 7;
    u16* vdst = C + 2 * EL + (size_t)gb * 262144 + s0;
#pragma unroll
    for (int j = 0; j < BN / 32; ++j) {
      const int col = j * 32 + grp;
      const int n = (colbase - 1024) + col, h = n >> 6, d = n & 63;
      uint4 w = *(const uint4*)(Ls + col * 64 + ((sl ^ (col & 7)) << 3));
      *(uint4*)(vdst + (size_t)h * 32768 + (size_t)d * 512 + sl * 8) = w;
    }
  }
}

// ---------------------------------------------------------------------------
// Fused attention: per block = (q-tile of 64 rows, one (b,h)).
// ctx[b,s,h*64+d] = softmax(mask(Q K^T)) V.  Q pre-scaled by 0.125.
// ---------------------------------------------------------------------------
__global__ __launch_bounds__(256)
void flash_attn(const u16* __restrict__ q, const u16* __restrict__ k,
                const u16* __restrict__ v, const unsigned char* __restrict__ pad,
                u16* __restrict__ ctx, int mtype)
{
  __shared__ __align__(16) u16 KVs[8192];      // 16 KB: K or V chunk (swizzled)
  __shared__ __align__(16) u16 Pw[4][2048];    // 4 KB per wave: P tile 16x128
  const int bh = blockIdx.y, b = bh >> 3, h = bh & 7;
  const int qt = blockIdx.x;
  const int tid = threadIdx.x, lane = tid & 63, wid = tid >> 6;
  const int l15 = lane & 15, quad = lane >> 4;
  const size_t bho = (size_t)bh * 32768;
  const int qrow = qt * 64 + wid * 16 + l15;       // A-operand row (this lane)
  const int qcd  = qt * 64 + wid * 16 + quad * 4;  // C-layout row base

  unsigned char* Ps = (unsigned char*)&Pw[0][0];
  if (tid < 128) ((uchar4*)Ps)[tid] = ((const uchar4*)(pad + b * 512))[tid];

  bf16x8 aq0 = *(const bf16x8*)(q + bho + (size_t)qrow * 64 + quad * 8);
  bf16x8 aq1 = *(const bf16x8*)(q + bho + (size_t)qrow * 64 + 32 + quad * 8);

  f32x4 S[32];
#pragma unroll
  for (int kc = 0; kc < 4; ++kc) {
    __syncthreads();
#pragma unroll
    for (int i = 0; i < 4; ++i) {             // stage K chunk [128 keys][64]
      const int s = tid + i * 256;
      const int row = s >> 3, c = (s & 7) ^ (row & 7);
      gload16(k + bho + (size_t)(kc * 128 + row) * 64 + c * 8, KVs + s * 8);
    }
    __syncthreads();
#pragma unroll
    for (int t = 0; t < 8; ++t) {
      const int sw = l15 & 7;
      bf16x8 b0 = *(const bf16x8*)(KVs + (t * 16 + l15) * 64 + (quad ^ sw) * 8);
      bf16x8 b1 = *(const bf16x8*)(KVs + (t * 16 + l15) * 64 + ((4 + quad) ^ sw) * 8);
      f32x4 z = {0.f, 0.f, 0.f, 0.f};
      z = __builtin_amdgcn_mfma_f32_16x16x32_bf16(aq0, b0, z, 0, 0, 0);
      S[kc * 8 + t] = __builtin_amdgcn_mfma_f32_16x16x32_bf16(aq1, b1, z, 0, 0, 0);
    }
  }

  unsigned pm = 0u;
#pragma unroll
  for (int t = 0; t < 32; ++t) pm |= (unsigned)(Ps[t * 16 + l15] != 0) << t;

  float inv[4];
#pragma unroll
  for (int r = 0; r < 4; ++r) {
    const int qg = qcd + r;
    float mx = -3.0e38f;
#pragma unroll
    for (int t = 0; t < 32; ++t) {
      const int col = t * 16 + l15;
      const bool m = ((pm >> t) & 1u) || (mtype == 1 && col > qg);
      const float val = m ? -1e9f : S[t][r];
      S[t][r] = val;
      mx = fmaxf(mx, val);
    }
#pragma unroll
    for (int o = 8; o > 0; o >>= 1) mx = fmaxf(mx, __shfl_xor(mx, o));
    float sm = 0.f;
#pragma unroll
    for (int t = 0; t < 32; ++t) { const float e = __expf(S[t][r] - mx); S[t][r] = e; sm += e; }
#pragma unroll
    for (int o = 8; o > 0; o >>= 1) sm += __shfl_xor(sm, o);
    inv[r] = 1.f / sm;
  }

  f32x4 O[4] = {};
  u16* myP = &Pw[wid][0];
#pragma unroll
  for (int kc = 0; kc < 4; ++kc) {
    __syncthreads();
#pragma unroll
    for (int i = 0; i < 4; ++i) {             // stage V chunk [64 dk][128 keys]
      const int s = tid + i * 256;
      const int row = s >> 4, c = (s & 15) ^ (row & 15);
      gload16(v + bho + (size_t)row * 512 + kc * 128 + c * 8, KVs + s * 8);
    }
#pragma unroll
    for (int t = 0; t < 8; ++t)
#pragma unroll
      for (int r = 0; r < 4; ++r) {
        const int rowq = quad * 4 + r;
        const int c = 2 * t + (l15 >> 3);
        myP[rowq * 128 + (c ^ rowq) * 8 + (l15 & 7)] = f2bf(S[kc * 8 + t][r] * inv[r]);
      }
    __syncthreads();
#pragma unroll
    for (int kk = 0; kk < 4; ++kk) {
      bf16x8 ap = *(const bf16x8*)(myP + l15 * 128 + ((kk * 4 + quad) ^ l15) * 8);
#pragma unroll
      for (int ni = 0; ni < 4; ++ni) {
        bf16x8 bv = *(const bf16x8*)(KVs + (ni * 16 + l15) * 128 + ((kk * 4 + quad) ^ l15) * 8);
        O[ni] = __builtin_amdgcn_mfma_f32_16x16x32_bf16(ap, bv, O[ni], 0, 0, 0);
      }
    }
  }

  const int token = b * 512 + qcd;
#pragma unroll
  for (int ni = 0; ni < 4; ++ni)
#pragma unroll
    for (int r = 0; r < 4; ++r)
      ctx[(size_t)(token + r) * 512 + h * 64 + ni * 16 + l15] = f2bf(O[ni][r]);
}

// ---------------------------------------------------------------------------
// Merged setup:
// z<48   -> weight transposes (fp32 [K,N] -> bf16 [N,K]); float4 read,
//           ushort4 write (both sides vectorized).
// 48..79 -> fp32->bf16 conversion of the 4 FFN weight groups (2x float4
//           read -> uint4 (16B) store, 8 elems/thread).
// z==80  -> build ewb (identity-augmented embedding weight, bf16 [512,64])
//           and biasE[512] = [0 x32, eb].
// z==81  -> embed-pre: x fp32 [8192,32] -> xbf bf16 [8192,64] (cols 32..63=0)
//           + pad flags (sum(x_row) <= -9999).
// ---------------------------------------------------------------------------
__global__ __launch_bounds__(256)
void prep_weights(const float* __restrict__ s0, const float* __restrict__ s1,
                  const float* __restrict__ s2, const float* __restrict__ s3,
                  const float* __restrict__ s4, const float* __restrict__ s5,
                  u16* __restrict__ outT,
                  const float* __restrict__ c0, const float* __restrict__ c1,
                  const float* __restrict__ c2, const float* __restrict__ c3,
                  u16* __restrict__ outC,
                  const float* __restrict__ ew, const float* __restrict__ eb,
                  u16* __restrict__ ewb, float* __restrict__ biasE,
                  const float* __restrict__ xe, const float* __restrict__ xd,
                  u16* __restrict__ xbf,
                  unsigned char* __restrict__ pe, unsigned char* __restrict__ pd)
{
  __shared__ float tile[32][33];
  const int z = blockIdx.z;
  const int tid = threadIdx.y * 32 + threadIdx.x;
  const int r  = tid >> 3;          // 0..31
  const int c4 = (tid & 7) * 4;     // 0,4,..,28
  if (z < 48) {
    const float* src; int zi;
    if      (z < 12) { src = s0; zi = z; }
    else if (z < 24) { src = s1; zi = z - 12; }
    else if (z < 36) { src = s2; zi = z - 24; }
    else if (z < 40) { src = s3; zi = z - 36; }
    else if (z < 44) { src = s4; zi = z - 40; }
    else             { src = s5; zi = z - 44; }
    const float* in = src + (size_t)zi * MAT;
    u16* o = outT + (size_t)z * MAT;
    // load: one float4 per thread covers the whole 32x32 tile
    float4 v = *(const float4*)(in + (size_t)(blockIdx.y * 32 + r) * 512 + blockIdx.x * 32 + c4);
    tile[r][c4 + 0] = v.x; tile[r][c4 + 1] = v.y;
    tile[r][c4 + 2] = v.z; tile[r][c4 + 3] = v.w;
    __syncthreads();
    // write: out[R][C] = tile[C_local][R_local]; thread -> 4 consecutive C
    ushort4 w;
    w.x = f2bf(tile[c4 + 0][r]);
    w.y = f2bf(tile[c4 + 1][r]);
    w.z = f2bf(tile[c4 + 2][r]);
    w.w = f2bf(tile[c4 + 3][r]);
    *(ushort4*)(o + (size_t)(blockIdx.x * 32 + r) * 512 + blockIdx.y * 32 + c4) = w;
  } else if (z < 80) {
    const int L = (z - 48) * 256 + blockIdx.y * 16 + blockIdx.x;  // 0..8191
    const size_t e0 = ((size_t)L * 256 + tid) * 8;
    const int tens = (int)(e0 >> 22);     // 4*WFT = 2^22
    const size_t local = e0 & (4 * WFT - 1);
    const float* srcs[4] = { c0, c1, c2, c3 };
    const float* src = srcs[tens];
    float4 v0 = *(const float4*)(src + local);
    float4 v1 = *(const float4*)(src + local + 4);
    ushort4 ua = { f2bf(v0.x), f2bf(v0.y), f2bf(v0.z), f2bf(v0.w) };
    ushort4 ub = { f2bf(v1.x), f2bf(v1.y), f2bf(v1.z), f2bf(v1.w) };
    uint4 w;
    w.x = (uint32_t)ua.x | ((uint32_t)ua.y << 16);
    w.y = (uint32_t)ua.z | ((uint32_t)ua.w << 16);
    w.z = (uint32_t)ub.x | ((uint32_t)ub.y << 16);
    w.w = (uint32_t)ub.z | ((uint32_t)ub.w << 16);
    *(uint4*)(outC + (size_t)tens * (4 * WFT) + local) = w;
  } else if (z == 80) {
    const int bxy = blockIdx.y * 16 + blockIdx.x;   // 0..255
    if (tid < 128) {
      const int row = bxy * 2 + (tid >> 6);         // 0..511
      const int c = tid & 63;
      float v;
      if (row < 32) v = (c == row) ? 1.f : 0.f;
      else          v = (c < 32) ? ew[(size_t)(row - 32) * 32 + c] : 0.f;
      ewb[(size_t)row * 64 + c] = f2bf(v);
    }
    if (bxy == 0) {
#pragma unroll
      for (int rep = 0; rep < 2; ++rep) {
        const int i = tid + rep * 256;
        biasE[i] = (i < 32) ? 0.f : eb[i - 32];
      }
    }
  } else {  // z == 81: embed-pre
    const int bxy = blockIdx.y * 16 + blockIdx.x;   // 0..255
    const int lw = tid & 31;
#pragma unroll
    for (int rep = 0; rep < 4; ++rep) {
      const int rr0 = bxy * 32 + rep * 8 + (tid >> 5);  // 0..8191
      const float* xsrc = (rr0 < 4096) ? xe : xd;
      const int rr = rr0 & 4095;
      const float v = xsrc[(size_t)rr * 32 + lw];
      float sm = v;
#pragma unroll
      for (int o = 16; o > 0; o >>= 1) sm += __shfl_xor(sm, o);
      if (lw == 0) {
        unsigned char* pv = (rr0 < 4096) ? pe : pd;
        pv[rr] = (sm <= -9999.f) ? 1 : 0;
      }
      u16* orow = xbf + (size_t)rr0 * 64;
      orow[lw] = f2bf(v);
      orow[32 + lw] = 0;
    }
  }
}

// wave-per-row LN(x + y), torch-style (ddof=1, /(std+eps)). 4 rows/block.
// out32 != nullptr: write fp32 to out32 instead of bf16 to out (final output).
__global__ __launch_bounds__(256)
void add_ln(const u16* __restrict__ x, const u16* __restrict__ y,
            const float* __restrict__ g, const float* __restrict__ bb,
            u16* __restrict__ out, float* __restrict__ out32)
{
  const int row  = blockIdx.x * 4 + (threadIdx.x >> 6);
  const int lane = threadIdx.x & 63;
  const int c0 = lane * 8;
  const size_t base = (size_t)row * Dm + c0;

  uint4 xr = *(const uint4*)(x + base);
  uint4 yr = *(const uint4*)(y + base);
  const u16* xh = (const u16*)&xr;
  const u16* yh = (const u16*)&yr;
  float z[8];
  float s = 0.f;
#pragma unroll
  for (int j = 0; j < 8; ++j) { z[j] = bf2f(xh[j]) + bf2f(yh[j]); s += z[j]; }
#pragma unroll
  for (int off = 32; off > 0; off >>= 1) s += __shfl_xor(s, off);
  const float mean = s * (1.f / 512.f);
  float ss = 0.f;
#pragma unroll
  for (int j = 0; j < 8; ++j) { z[j] -= mean; ss += z[j] * z[j]; }
#pragma unroll
  for (int off = 32; off > 0; off >>= 1) ss += __shfl_xor(ss, off);
  const float stdv = sqrtf(ss * (1.f / 511.f));
  const float inv = 1.f / (stdv + 1e-6f);

  float4 g0 = *(const float4*)(g + c0),  g1 = *(const float4*)(g + c0 + 4);
  float4 b0 = *(const float4*)(bb + c0), b1 = *(const float4*)(bb + c0 + 4);
  float gv[8] = { g0.x, g0.y, g0.z, g0.w, g1.x, g1.y, g1.z, g1.w };
  float bv[8] = { b0.x, b0.y, b0.z, b0.w, b1.x, b1.y, b1.z, b1.w };
  float o[8];
#pragma unroll
  for (int j = 0; j < 8; ++j) o[j] = gv[j] * z[j] * inv + bv[j];
  if (out32) {
    float4 w0 = { o[0], o[1], o[2], o[3] };
    float4 w1 = { o[4], o[5], o[6], o[7] };
    *(float4*)(out32 + base) = w0;
    *(float4*)(out32 + base + 4) = w1;
  } else {
    uint4 ow;
    u16* oh = (u16*)&ow;
#pragma unroll
    for (int j = 0; j < 8; ++j) oh[j] = f2bf(o[j]);
    *(uint4*)(out + base) = ow;
  }
}

extern "C" void kernel_launch(void* const* d_in, const int* in_sizes, int n_in,
                              void* d_out, int out_size, void* d_ws, size_t ws_size,
                              hipStream_t stream)
{
  (void)in_sizes; (void)n_in; (void)out_size;
  const float* enc_in   = (const float*)d_in[0];
  const float* dec_in   = (const float*)d_in[1];
  const float* emb_w    = (const float*)d_in[2];
  const float* emb_b    = (const float*)d_in[3];
  const float* pos      = (const float*)d_in[4];
  const float* e_qkv_w  = (const float*)d_in[5];
  const float* e_qkv_b  = (const float*)d_in[6];
  const float* e_pw     = (const float*)d_in[7];
  const float* e_pb     = (const float*)d_in[8];
  const float* e_ln1    = (const float*)d_in[9];
  const float* e_w1     = (const float*)d_in[10];
  const float* e_b1     = (const float*)d_in[11];
  const float* e_w2     = (const float*)d_in[12];
  const float* e_b2     = (const float*)d_in[13];
  const float* e_ln2    = (const float*)d_in[14];
  const float* ds_qkv_w = (const float*)d_in[15];
  const float* ds_qkv_b = (const float*)d_in[16];
  const float* ds_pw    = (const float*)d_in[17];
  const float* ds_pb    = (const float*)d_in[18];
  const float* d_ln1    = (const float*)d_in[19];
  const float* dc_qkv_w = (const float*)d_in[20];
  const float* dc_qkv_b = (const float*)d_in[21];
  const float* dc_pw    = (const float*)d_in[22];
  const float* dc_pb    = (const float*)d_in[23];
  const float* d_ln2    = (const float*)d_in[24];
  const float* d_w1     = (const float*)d_in[25];
  const float* d_b1     = (const float*)d_in[26];
  const float* d_w2     = (const float*)d_in[27];
  const float* d_b2     = (const float*)d_in[28];
  const float* d_ln3    = (const float*)d_in[29];

  u16* ws  = (u16*)d_ws;
  u16* enc = ws;             // EL   (enc|dec contiguous -> one embed GEMM)
  u16* dec = ws + EL;        // EL
  u16* qb  = ws + 2 * EL;    // EL [B,H,S,DK]  (K at +EL, V^T at +2EL)
  u16* kb  = ws + 3 * EL;    // EL [B,H,S,DK]
  u16* vT  = ws + 4 * EL;    // EL [B,H,DK,S]
  u16* ctx = ws + 5 * EL;    // EL [B,S,H*DK]
  u16* t1  = ws + 6 * EL;    // EL
  u16* hff = ws + 7 * EL;    // 4*EL [B,S,Dff]
  u16* wT  = ws + 15 * EL;   // 6*EL: 48 transposed bf16 512x512 matrices
  unsigned char* padE = (unsigned char*)(ws + 21 * EL);   // TOK bytes
  unsigned char* padD = padE + TOK;                       // TOK bytes
  u16* xbf   = ws + 21 * EL + 8192;        // 8192x64 bf16 (512K elems)
  u16* ewb   = xbf + (size_t)8192 * 64;    // 512x64 bf16 (32K elems)
  float* biasE = (float*)(ewb + 32768);    // 512 fp32
  u16* wfAll = ws + 22 * EL; // 8*EL: [e_w1(4L), e_w2(4L), d_w1(4L), d_w2(4L)] bf16
  if (ws_size < 30 * EL * 2 + 2 * TOK) return;

  prep_weights<<<dim3(16, 16, 82), dim3(32, 8), 0, stream>>>(
      e_qkv_w, ds_qkv_w, dc_qkv_w, e_pw, ds_pw, dc_pw, wT,
      e_w1, e_w2, d_w1, d_w2, wfAll,
      emb_w, emb_b, ewb, biasE,
      enc_in, dec_in, xbf, padE, padD);
  // embedding as identity-augmented GEMM: [8192,64] @ ewb[512,64]^T + biasE + pos
  gemm_tile<64, 128, 4><<<dim3(4, 128, 1), 256, 0, stream>>>(
      xbf, ewb, biasE, enc, 64, 64, 0, 64, 0, 512, 0, 5, 0, 0, nullptr, 0, pos);

  // full MHA sublayer: x = LN(x + proj(flash_attn(q(qsrc), k(kvsrc), v(kvsrc))))
  auto attention = [&](const u16* qsrc, const u16* kvsrc, const u16* wq3, const float* b3,
                       const u16* pwT, const float* pb, const float* ln,
                       const unsigned char* pad, int mtype, u16* x) {
    if (qsrc == kvsrc) {
      // fused QKV: [4096,512] x [1536,512]^T -> qb/kb/vT
      gemm_tile<64, 128, 0><<<dim3(12, 64, 1), 256, 0, stream>>>(
          qsrc, wq3, b3, qb, 512, 512, 0, 512, 0, 0, 0, 4, 0, 0, nullptr, 0, nullptr);
    } else {
      // merged cross Q (x<4: A=qsrc, cols 0..511) + KV (x>=4: A=kvsrc, cols 512..1535)
      gemm_tile<64, 128, 0><<<dim3(12, 64, 1), 256, 0, stream>>>(
          qsrc, wq3, b3, qb, 512, 512, 0, 512, 0, 0, 0, 4, 0, 0, kvsrc, 4, nullptr);
    }
    flash_attn<<<dim3(8, 64), 256, 0, stream>>>(qb, kb, vT, pad, ctx, mtype);
    gemm_tile<64, 64, 1><<<dim3(8, 64, 1), 256, 0, stream>>>(
        ctx, pwT, pb, t1, 512, 512, 0, 512, 0, 512, 0, 0, 0, 0, nullptr, 0, nullptr);
    add_ln<<<TOK / 4, 256, 0, stream>>>(x, t1, ln, ln + 512, x, nullptr);
  };

  auto ffn = [&](u16* x, const u16* w1b, const float* b1, const u16* w2b,
                 const float* b2, const float* ln, float* o32) {
    gemm_tile<64, 128, 2><<<dim3(16, 64, 1), 256, 0, stream>>>(
        x, w1b, b1, hff, 512, 512, 0, 512, 0, 2048, 0, 0, 1, 0, nullptr, 0, nullptr);
    gemm_tile<64, 64, 3><<<dim3(8, 64, 1), 256, 0, stream>>>(
        hff, w2b, b2, t1, 2048, 2048, 0, 2048, 0, 512, 0, 0, 0, 0, nullptr, 0, nullptr);
    add_ln<<<TOK / 4, 256, 0, stream>>>(x, t1, ln, ln + 512, x, o32);
  };

  for (int i = 0; i < NL; ++i) {
    attention(enc, enc, wT + (size_t)(i * 3) * MAT, e_qkv_b + i * 3 * 512,
              wT + (size_t)(36 + i) * MAT, e_pb + i * 512, e_ln1 + i * 1024, padE, 0, enc);
    ffn(enc, wfAll + (size_t)i * WFT, e_b1 + i * Dff,
        wfAll + 4 * WFT + (size_t)i * WFT, e_b2 + i * Dm, e_ln2 + i * 1024, nullptr);
  }

  for (int i = 0; i < NL; ++i) {
    attention(dec, dec, wT + (size_t)(12 + i * 3) * MAT, ds_qkv_b + i * 3 * 512,
              wT + (size_t)(40 + i) * MAT, ds_pb + i * 512, d_ln1 + i * 1024, padD, 1, dec);
    attention(dec, enc, wT + (size_t)(24 + i * 3) * MAT, dc_qkv_b + i * 3 * 512,
              wT + (size_t)(44 + i) * MAT, dc_pb + i * 512, d_ln2 + i * 1024, padE, 2, dec);
    ffn(dec, wfAll + 8 * WFT + (size_t)i * WFT, d_b1 + i * Dff,
        wfAll + 12 * WFT + (size_t)i * WFT, d_b2 + i * Dm, d_ln3 + i * 1024,
        (i == NL - 1) ? (float*)d_out : nullptr);
  }
}